// Round 18
// baseline (943.382 us; speedup 1.0000x reference)
//
#include <hip/hip_runtime.h>
#include <stdint.h>

#define DEV __device__ __forceinline__

typedef __attribute__((ext_vector_type(8))) short bf16x8;
typedef __attribute__((ext_vector_type(4))) float f32x4;
typedef __attribute__((ext_vector_type(4))) short s16x4;

DEV short f2bf(float f) {
    union { float f; unsigned u; } v; v.f = f;
    unsigned r = v.u + 0x7fffu + ((v.u >> 16) & 1u);
    return (short)(r >> 16);
}

// packed f32x2 -> bf16x2 (RNE), single VALU op
DEV uint32_t cvtpk(float lo, float hi) {
    uint32_t r;
    asm("v_cvt_pk_bf16_f32 %0, %1, %2" : "=v"(r) : "v"(lo), "v"(hi));
    return r;
}

typedef const unsigned int __attribute__((address_space(1)))* gp1;
typedef unsigned int __attribute__((address_space(3)))* lp3;

DEV void gload16(const void* g, void* l) {
    __builtin_amdgcn_global_load_lds((gp1)g, (lp3)l, 16, 0, 0);
}

DEV void wait1_barrier() { asm volatile("s_waitcnt vmcnt(1)\ns_barrier" ::: "memory"); }
DEV void wait0_barrier() { asm volatile("s_waitcnt vmcnt(0)\ns_barrier" ::: "memory"); }

// ------------- merged weight transpose + fp32->bf16 (4 jobs) -----------
__global__ __launch_bounds__(256) void tcvt4(
    const float* __restrict__ W0, short* __restrict__ T0,
    const float* __restrict__ W1, short* __restrict__ T1,
    const float* __restrict__ W2, short* __restrict__ T2,
    const float* __restrict__ W3, short* __restrict__ T3)
{
    __shared__ float t[32][33];
    int bid = blockIdx.x;
    const float* W; short* WT; int K, N, nx, lb;
    if (bid < 1728)      { W = W0; WT = T0; K = 768;  N = 2304; nx = 72; lb = bid; }
    else if (bid < 2304) { W = W1; WT = T1; K = 768;  N = 768;  nx = 24; lb = bid - 1728; }
    else if (bid < 4608) { W = W2; WT = T2; K = 768;  N = 3072; nx = 96; lb = bid - 2304; }
    else                 { W = W3; WT = T3; K = 3072; N = 768;  nx = 24; lb = bid - 4608; }
    int n0 = (lb % nx) * 32, k0 = (lb / nx) * 32;
    int tx = threadIdx.x & 31, ty = threadIdx.x >> 5;
#pragma unroll
    for (int i = 0; i < 32; i += 8)
        t[ty + i][tx] = W[(size_t)(k0 + ty + i) * N + n0 + tx];
    __syncthreads();
#pragma unroll
    for (int i = 0; i < 32; i += 8)
        WT[(size_t)(n0 + ty + i) * K + k0 + tx] = f2bf(t[tx][ty + i]);
}

// ---------------- LayerNorm fp32 -> bf16, one wave per row (C=768) -----
__global__ __launch_bounds__(256) void ln_bf16(
    const float* __restrict__ x, const float* __restrict__ gam,
    const float* __restrict__ bet, short* __restrict__ out)
{
    const int w = threadIdx.x >> 6, lane = threadIdx.x & 63;
    const size_t row = (size_t)blockIdx.x * 4 + w;
    const float* xr = x + row * 768;
    float4 v[3];
    float s = 0.f, ss = 0.f;
#pragma unroll
    for (int k = 0; k < 3; ++k) {
        v[k] = *(const float4*)(xr + k * 256 + lane * 4);
        s  += v[k].x + v[k].y + v[k].z + v[k].w;
        ss += v[k].x * v[k].x + v[k].y * v[k].y + v[k].z * v[k].z + v[k].w * v[k].w;
    }
#pragma unroll
    for (int i = 1; i < 64; i <<= 1) { s += __shfl_xor(s, i, 64); ss += __shfl_xor(ss, i, 64); }
    const float inv = 1.f / 768.f;
    float mu = s * inv;
    float var = ss * inv - mu * mu;
    float rstd = rsqrtf(var + 1e-5f);
#pragma unroll
    for (int k = 0; k < 3; ++k) {
        int c = k * 256 + lane * 4;
        float vv[4] = { v[k].x, v[k].y, v[k].z, v[k].w };
        s16x4 o;
#pragma unroll
        for (int j = 0; j < 4; ++j)
            o[j] = f2bf((vv[j] - mu) * rstd * gam[c + j] + bet[c + j]);
        *(s16x4*)(out + row * 768 + c) = o;
    }
}

// ===== 256x128x32 bf16 GEMM, 8 waves (4M x 2N), 64x64/wave, 2 buffers ===
// 64x64 wave-tiles halve LDS reads/FLOP vs 32x32 (reads/FLOP ~ 1/h + 1/w);
// 2 buffers x 24KB = 48KB -> 3 blocks/CU = 24 waves/CU (vs r13's 3-buf
// 72KB = 2 blocks = the occupancy that killed it). Layout + epilogue are
// verbatim from the correctness-verified r13 kernel; only the schedule is
// 2-buf: stage(next) issued BEFORE compute(cur), one wait0-barrier/step.
// MODE 0: QKV scatter (q scaled 0.125*log2e, v transposed [B,H,D,N]).
// MODE 2: out_bf16 = gelu(acc + bias).
template<int MODE>
DEV void gemm_body_big(
    const short* __restrict__ A, const short* __restrict__ Bt,
    int M, int N, int K,
    const float* __restrict__ bias, short* __restrict__ outb,
    short* __restrict__ qo, short* __restrict__ ko, short* __restrict__ vo,
    char* lds)
{
    const int tid = threadIdx.x;
    const int w = tid >> 6, lane = tid & 63;
    const int g = lane >> 4, l15 = lane & 15;
    const int brow = blockIdx.x * 256, bcol = blockIdx.y * 128;
    const int wr = w >> 1, wc = w & 1;        // 4M x 2N waves
    f32x4 acc[4][4] = {};

    // loop-invariant LDS read byte-offsets (within one 24KB buffer:
    // A = 16KB (256 rows x 64B), B at +16384 (128 rows x 64B))
    int aoff[4], boff[4];
#pragma unroll
    for (int m = 0; m < 4; ++m) {
        int ra = wr * 64 + m * 16 + l15;
        aoff[m] = ra * 64 + ((g * 16) ^ (((ra >> 1) & 3) << 4));
        int rb = wc * 64 + m * 16 + l15;
        boff[m] = 16384 + rb * 64 + ((g * 16) ^ (((rb >> 1) & 3) << 4));
    }
    // staging: 2 A-loads + 1 B-load per thread per step
    const int L = tid * 16;
    const int r0 = L >> 6, bb = L & 63;
    const int bs = bb ^ (((r0 >> 1) & 3) << 4);   // row+128 has same swizzle
    const char* pA0 = (const char*)(A  + (size_t)(brow + r0) * K) + bs;
    const char* pA1 = (const char*)(A  + (size_t)(brow + 128 + r0) * K) + bs;
    const char* pB  = (const char*)(Bt + (size_t)(bcol + r0) * K) + bs;
    const int dA0 = L, dA1 = 8192 + L, dB = 16384 + L;

#define GSTAGE(BUF, OFF) do { \
    gload16(pA0 + (OFF), lds + (BUF) * 24576 + dA0); \
    gload16(pA1 + (OFF), lds + (BUF) * 24576 + dA1); \
    gload16(pB  + (OFF), lds + (BUF) * 24576 + dB); } while (0)

#define COMPUTE(BUF) do { \
    bf16x8 af[4], bfg[4]; \
    _Pragma("unroll") \
    for (int m = 0; m < 4; ++m) { \
        af[m]  = *(const bf16x8*)(lds + (BUF) * 24576 + aoff[m]); \
        bfg[m] = *(const bf16x8*)(lds + (BUF) * 24576 + boff[m]); \
    } \
    _Pragma("unroll") \
    for (int m = 0; m < 4; ++m) \
        _Pragma("unroll") \
        for (int n = 0; n < 4; ++n) \
            acc[m][n] = __builtin_amdgcn_mfma_f32_16x16x32_bf16(af[m], bfg[n], acc[m][n], 0, 0, 0); \
    } while (0)

    const int KT = K >> 5;            // 24 (even)
    GSTAGE(0, 0);
    wait0_barrier();                  // buf0 ready
    for (int mi = 0; mi < KT / 2 - 1; ++mi) {
        GSTAGE(1, 64);  COMPUTE(0); wait0_barrier();
        GSTAGE(0, 128); COMPUTE(1); wait0_barrier();
        pA0 += 128; pA1 += 128; pB += 128;
    }
    GSTAGE(1, 64); COMPUTE(0); wait0_barrier();
    COMPUTE(1);
#undef GSTAGE
#undef COMPUTE

#pragma unroll
    for (int m = 0; m < 4; ++m) {
#pragma unroll
        for (int n = 0; n < 4; ++n) {
#pragma unroll
            for (int j = 0; j < 4; ++j) {
                int r = brow + wr * 64 + m * 16 + g * 4 + j;
                int c = bcol + wc * 64 + n * 16 + l15;
                float v = acc[m][n][j];
                if (MODE == 0) {
                    int which = c / 768, cc = c % 768;
                    int h = cc >> 6, d = cc & 63;
                    int b_ = r >> 11, nn = r & 2047;
                    size_t bh = (size_t)b_ * 12 + h;
                    // Q pre-scaled by 0.125*log2(e) so attention uses exp2
                    if (which == 0)      qo[(bh * 2048 + nn) * 64 + d] = f2bf(v * 0.18033688011112042f);
                    else if (which == 1) ko[(bh * 2048 + nn) * 64 + d] = f2bf(v);
                    else                 vo[(bh * 64 + d) * 2048 + nn] = f2bf(v);
                } else {
                    float t = v + bias[c];
                    float ge = 0.5f * t * (1.0f + erff(t * 0.70710678118654752f));
                    outb[(size_t)r * N + c] = f2bf(ge);
                }
            }
        }
    }
}

__global__ __launch_bounds__(512, 6) void gb_qkv(
    const short* A, const short* Bt, int M, int N, int K,
    short* qo, short* ko, short* vo)
{
    __shared__ __align__(16) char lds[49152];
    gemm_body_big<0>(A, Bt, M, N, K, nullptr, nullptr, qo, ko, vo, lds);
}
__global__ __launch_bounds__(512, 6) void gb_fc1(
    const short* A, const short* Bt, int M, int N, int K,
    const float* bias, short* outb)
{
    __shared__ __align__(16) char lds[49152];
    gemm_body_big<2>(A, Bt, M, N, K, bias, outb, nullptr, nullptr, nullptr, lds);
}

// -------- 128x128x32 bf16 GEMM, 16 waves / 1024 threads (r15-proven) ----
// Kept for the N=768, grid-limited shapes (proj, fc2).
// MODE 1: fp32 = acc + bias + resid.
template<int MODE>
DEV void gemm_body(
    const short* __restrict__ A, const short* __restrict__ Bt,
    int M, int N, int K,
    const float* __restrict__ bias, const float* __restrict__ resid,
    float* __restrict__ outf, char* lds)
{
    const int tid = threadIdx.x;
    const int w = tid >> 6, lane = tid & 63;
    const int g = lane >> 4, l15 = lane & 15;
    const int brow = blockIdx.x * 128, bcol = blockIdx.y * 128;
    const int wr = w >> 2, wc = w & 3;          // 4M x 4N waves
    f32x4 acc[2][2] = {};

    int aoff[2], boff[2];
#pragma unroll
    for (int m = 0; m < 2; ++m) {
        int ra = wr * 32 + m * 16 + l15;
        aoff[m] = ra * 64 + ((g * 16) ^ (((ra >> 1) & 3) << 4));
    }
#pragma unroll
    for (int n = 0; n < 2; ++n) {
        int rb = wc * 32 + n * 16 + l15;
        boff[n] = 8192 + rb * 64 + ((g * 16) ^ (((rb >> 1) & 3) << 4));
    }
    const int dStage = tid * 16;
    const char* pSrc;
    {
        int r = dStage >> 6, b = dStage & 63;
        int bs = b ^ (((r >> 1) & 3) << 4);
        pSrc = (tid < 512)
             ? (const char*)(A  + (size_t)(brow + r) * K) + bs
             : (const char*)(Bt + (size_t)(bcol + (r - 128)) * K) + bs;
    }

#define GSTAGE(BUF, OFF) gload16(pSrc + (OFF), lds + (BUF) * 16384 + dStage)

    const int KT = K >> 5;            // 24 or 96: divisible by 3
    GSTAGE(0, 0);
    GSTAGE(1, 64);
    wait1_barrier();

    const int NM = KT / 3;
    for (int mi = 0; mi < NM; ++mi) {
#pragma unroll
        for (int u = 0; u < 3; ++u) {
            const int s = mi * 3 + u;
            if (s + 2 < KT) GSTAGE((u + 2) % 3, (u + 2) * 64);
            bf16x8 af[2], bfg[2];
#pragma unroll
            for (int m = 0; m < 2; ++m)
                af[m]  = *(const bf16x8*)(lds + u * 16384 + aoff[m]);
#pragma unroll
            for (int n = 0; n < 2; ++n)
                bfg[n] = *(const bf16x8*)(lds + u * 16384 + boff[n]);
#pragma unroll
            for (int m = 0; m < 2; ++m)
#pragma unroll
                for (int n = 0; n < 2; ++n)
                    acc[m][n] = __builtin_amdgcn_mfma_f32_16x16x32_bf16(af[m], bfg[n], acc[m][n], 0, 0, 0);
            if (s + 1 < KT) {
                if (s + 2 < KT) wait1_barrier();
                else            wait0_barrier();
            }
        }
        pSrc += 192;
    }
#undef GSTAGE

#pragma unroll
    for (int m = 0; m < 2; ++m)
#pragma unroll
        for (int n = 0; n < 2; ++n)
#pragma unroll
            for (int j = 0; j < 4; ++j) {
                int r = brow + wr * 32 + m * 16 + g * 4 + j;
                int c = bcol + wc * 32 + n * 16 + l15;
                outf[(size_t)r * N + c] = acc[m][n][j] + bias[c] + resid[(size_t)r * N + c];
            }
}

__global__ __launch_bounds__(1024, 8) void g_proj(
    const short* A, const short* Bt, int M, int N, int K,
    const float* bias, const float* resid, float* outf)
{
    __shared__ __align__(16) char lds[49152];
    gemm_body<1>(A, Bt, M, N, K, bias, resid, outf, lds);
}
__global__ __launch_bounds__(1024, 8) void g_fc2(
    const short* A, const short* Bt, int M, int N, int K,
    const float* bias, const float* resid, float* outf)
{
    __shared__ __align__(16) char lds[49152];
    gemm_body<1>(A, Bt, M, N, K, bias, resid, outf, lds);
}

// ---------------- flash attention (r17, unchanged) ----------------------
__global__ __launch_bounds__(256, 3) void attn_fwd(
    const short* __restrict__ Q, const short* __restrict__ Kg,
    const short* __restrict__ Vt, short* __restrict__ Y)
{
    __shared__ __align__(16) char alds[43008];
    const int tid = threadIdx.x, w = tid >> 6, lane = tid & 63;
    const int g = lane >> 4, l15 = lane & 15;
    const int bid = blockIdx.y * gridDim.x + blockIdx.x;
    const int nwg = gridDim.x * gridDim.y;       // 768, % 8 == 0
    const int logical = (bid & 7) * (nwg >> 3) + (bid >> 3);
    const int bh = logical >> 4;
    const int q0 = (logical & 15) * 128 + w * 32;
    const short* Qb = Q  + (size_t)bh * 2048 * 64;
    const short* Kb = Kg + (size_t)bh * 2048 * 64;
    const short* Vb = Vt + (size_t)bh * 64 * 2048;

    bf16x8 qf[2][2];
#pragma unroll
    for (int m = 0; m < 2; ++m)
#pragma unroll
        for (int kk = 0; kk < 2; ++kk)
            qf[m][kk] = *(const bf16x8*)(Qb + (size_t)(q0 + m * 16 + l15) * 64 + kk * 32 + g * 8);

    f32x4 accO[2][4] = {};
    float lpart[2] = { 0.f, 0.f };

    int koff[2][2], voff[4], poff[2], pwoff[2][2];
#pragma unroll
    for (int n = 0; n < 2; ++n) {
        int key = n * 16 + l15;
#pragma unroll
        for (int kk = 0; kk < 2; ++kk)
            koff[kk][n] = key * 128 + ((kk * 64 + g * 16) ^ ((key & 7) << 4));
    }
#pragma unroll
    for (int n = 0; n < 4; ++n) {
        int d = n * 16 + l15;
        voff[n] = 16384 + d * 64 + ((g * 16) ^ (((d >> 1) & 3) << 4));
    }
#pragma unroll
    for (int m = 0; m < 2; ++m) {
        int qr = m * 16 + l15;
        poff[m] = 32768 + w * 2560 + qr * 80 + g * 16;   // stride-80 P rows
#pragma unroll
        for (int n = 0; n < 2; ++n)
            pwoff[m][n] = 32768 + w * 2560 + qr * 80 + n * 32 + g * 8;
    }
    int dK, dV; const char* pK3; const char* pV3;
    {
        int bb = w * 1024;
        int L = bb + lane * 16;
        int rk = L >> 7, bk_ = L & 127;
        int bsk = bk_ ^ ((rk & 7) << 4);
        dK = bb;
        pK3 = (const char*)(Kb + (size_t)rk * 64) + bsk;
        int rv = L >> 6, bv = L & 63;
        int bsv = bv ^ (((rv >> 1) & 3) << 4);
        dV = bb;
        pV3 = (const char*)(Vb + (size_t)rv * 2048) + bsv;
    }

#define ASTAGE(SLOT) do { \
    gload16(pK3, alds + dK + (SLOT) * 4096); \
    gload16(pV3, alds + 16384 + dV + (SLOT) * 4096); \
    pK3 += 4096; pV3 += 64; } while (0)

#define ACOMPUTE(SLOT) do { \
    f32x4 s2[2][2] = {}; \
    __builtin_amdgcn_s_setprio(1); \
    _Pragma("unroll") \
    for (int kk = 0; kk < 2; ++kk) { \
        bf16x8 kf[2]; \
        _Pragma("unroll") \
        for (int n = 0; n < 2; ++n) \
            kf[n] = *(const bf16x8*)(alds + (SLOT) * 4096 + koff[kk][n]); \
        _Pragma("unroll") \
        for (int m = 0; m < 2; ++m) \
            _Pragma("unroll") \
            for (int n = 0; n < 2; ++n) \
                s2[m][n] = __builtin_amdgcn_mfma_f32_16x16x32_bf16(kf[n], qf[m][kk], s2[m][n], 0, 0, 0); \
    } \
    __builtin_amdgcn_s_setprio(0); \
    _Pragma("unroll") \
    for (int m = 0; m < 2; ++m) \
        _Pragma("unroll") \
        for (int n = 0; n < 2; ++n) { \
            float e0 = __builtin_amdgcn_exp2f(s2[m][n][0]); \
            float e1 = __builtin_amdgcn_exp2f(s2[m][n][1]); \
            float e2 = __builtin_amdgcn_exp2f(s2[m][n][2]); \
            float e3 = __builtin_amdgcn_exp2f(s2[m][n][3]); \
            lpart[m] += (e0 + e1) + (e2 + e3); \
            uint2 pk; pk.x = cvtpk(e0, e1); pk.y = cvtpk(e2, e3); \
            *(uint2*)(alds + pwoff[m][n]) = pk; \
        } \
    __builtin_amdgcn_s_setprio(1); \
    { \
        bf16x8 vf[4], pf[2]; \
        _Pragma("unroll") \
        for (int n = 0; n < 4; ++n) \
            vf[n] = *(const bf16x8*)(alds + (SLOT) * 4096 + voff[n]); \
        _Pragma("unroll") \
        for (int m = 0; m < 2; ++m) \
            pf[m] = *(const bf16x8*)(alds + poff[m]); \
        _Pragma("unroll") \
        for (int m = 0; m < 2; ++m) \
            _Pragma("unroll") \
            for (int n = 0; n < 4; ++n) \
                accO[m][n] = __builtin_amdgcn_mfma_f32_16x16x32_bf16(pf[m], vf[n], accO[m][n], 0, 0, 0); \
    } \
    __builtin_amdgcn_s_setprio(0); } while (0)

    // prologue: tiles 0,1 into slots 0,1; full drain
    ASTAGE(0);
    ASTAGE(1);
    wait0_barrier();

    // 15 full 4-tile rounds (two 2-tile windows each)
    for (int om = 0; om < 15; ++om) {
        ASTAGE(2); ACOMPUTE(0); ASTAGE(3); ACOMPUTE(1); wait0_barrier();
        ASTAGE(0); ACOMPUTE(2); ASTAGE(1); ACOMPUTE(3); wait0_barrier();
    }
    // tail: tiles 60..63
    ASTAGE(2); ACOMPUTE(0); ASTAGE(3); ACOMPUTE(1); wait0_barrier();
    ACOMPUTE(2); ACOMPUTE(3);

#undef ASTAGE
#undef ACOMPUTE

#pragma unroll
    for (int m = 0; m < 2; ++m) {
        lpart[m] += __shfl_xor(lpart[m], 16, 64);
        lpart[m] += __shfl_xor(lpart[m], 32, 64);
    }

    int b_ = bh / 12, h = bh % 12;
#pragma unroll
    for (int m = 0; m < 2; ++m) {
        float linv[4];
#pragma unroll
        for (int j = 0; j < 4; ++j)
            linv[j] = 1.0f / __shfl(lpart[m], g * 4 + j, 64);
#pragma unroll
        for (int n = 0; n < 4; ++n)
#pragma unroll
            for (int j = 0; j < 4; ++j) {
                int qq = q0 + m * 16 + g * 4 + j;
                int d = n * 16 + l15;
                Y[((size_t)b_ * 2048 + qq) * 768 + h * 64 + d] = f2bf(accO[m][n][j] * linv[j]);
            }
    }
}

// ---------------- launcher ---------------------------------------------
extern "C" void kernel_launch(void* const* d_in, const int* in_sizes, int n_in,
                              void* d_out, int out_size, void* d_ws, size_t ws_size,
                              hipStream_t stream)
{
    const float* x      = (const float*)d_in[0];
    const float* ln1_g  = (const float*)d_in[1];
    const float* ln1_b  = (const float*)d_in[2];
    const float* w_qkv  = (const float*)d_in[3];
    const float* w_proj = (const float*)d_in[4];
    const float* b_proj = (const float*)d_in[5];
    const float* ln2_g  = (const float*)d_in[6];
    const float* ln2_b  = (const float*)d_in[7];
    const float* w_fc1  = (const float*)d_in[8];
    const float* b_fc1  = (const float*)d_in[9];
    const float* w_fc2  = (const float*)d_in[10];
    const float* b_fc2  = (const float*)d_in[11];

    char* ws = (char*)d_ws;
    size_t off = 0;
    auto alloc = [&](size_t bytes) -> void* {
        void* p = ws + off; off += (bytes + 255) & ~(size_t)255; return p;
    };
    short* wqkvT = (short*)alloc((size_t)2304 * 768 * 2);
    short* wprojT= (short*)alloc((size_t)768 * 768 * 2);
    short* wfc1T = (short*)alloc((size_t)3072 * 768 * 2);
    short* wfc2T = (short*)alloc((size_t)768 * 3072 * 2);
    short* h1    = (short*)alloc((size_t)8192 * 768 * 2);
    short* qb    = (short*)alloc((size_t)48 * 2048 * 64 * 2);
    short* kb    = (short*)alloc((size_t)48 * 2048 * 64 * 2);
    short* vtb   = (short*)alloc((size_t)48 * 64 * 2048 * 2);
    short* yb    = (short*)alloc((size_t)8192 * 768 * 2);
    float* X1    = (float*)alloc((size_t)8192 * 768 * 4);
    short* h2    = (short*)alloc((size_t)8192 * 768 * 2);
    short* h3    = (short*)alloc((size_t)8192 * 3072 * 2);

    tcvt4<<<6912, 256, 0, stream>>>(w_qkv, wqkvT, w_proj, wprojT,
                                    w_fc1, wfc1T, w_fc2, wfc2T);

    ln_bf16<<<2048, 256, 0, stream>>>(x, ln1_g, ln1_b, h1);

    gb_qkv<<<dim3(32, 18), 512, 0, stream>>>(h1, wqkvT, 8192, 2304, 768, qb, kb, vtb);

    attn_fwd<<<dim3(16, 48), 256, 0, stream>>>(qb, kb, vtb, yb);

    g_proj<<<dim3(64, 6), 1024, 0, stream>>>(yb, wprojT, 8192, 768, 768, b_proj, x, X1);

    ln_bf16<<<2048, 256, 0, stream>>>(X1, ln2_g, ln2_b, h2);

    gb_fc1<<<dim3(32, 24), 512, 0, stream>>>(h2, wfc1T, 8192, 3072, 768, b_fc1, h3);

    g_fc2<<<dim3(64, 6), 1024, 0, stream>>>(h3, wfc2T, 8192, 768, 3072, b_fc2, X1, (float*)d_out);
}

// Round 19
// 261.667 us; speedup vs baseline: 3.6053x; 3.6053x over previous
//
#include <hip/hip_runtime.h>
#include <stdint.h>

#define DEV __device__ __forceinline__

typedef __attribute__((ext_vector_type(8))) short bf16x8;
typedef __attribute__((ext_vector_type(4))) float f32x4;
typedef __attribute__((ext_vector_type(4))) short s16x4;

DEV short f2bf(float f) {
    union { float f; unsigned u; } v; v.f = f;
    unsigned r = v.u + 0x7fffu + ((v.u >> 16) & 1u);
    return (short)(r >> 16);
}

// packed f32x2 -> bf16x2 (RNE), single VALU op
DEV uint32_t cvtpk(float lo, float hi) {
    uint32_t r;
    asm("v_cvt_pk_bf16_f32 %0, %1, %2" : "=v"(r) : "v"(lo), "v"(hi));
    return r;
}

typedef const unsigned int __attribute__((address_space(1)))* gp1;
typedef unsigned int __attribute__((address_space(3)))* lp3;

DEV void gload16(const void* g, void* l) {
    __builtin_amdgcn_global_load_lds((gp1)g, (lp3)l, 16, 0, 0);
}

DEV void wait4_barrier() { asm volatile("s_waitcnt vmcnt(4)\ns_barrier" ::: "memory"); }
DEV void wait2_barrier() { asm volatile("s_waitcnt vmcnt(2)\ns_barrier" ::: "memory"); }
DEV void wait1_barrier() { asm volatile("s_waitcnt vmcnt(1)\ns_barrier" ::: "memory"); }
DEV void wait0_barrier() { asm volatile("s_waitcnt vmcnt(0)\ns_barrier" ::: "memory"); }

// ------------- merged weight transpose + fp32->bf16 (4 jobs) -----------
__global__ __launch_bounds__(256) void tcvt4(
    const float* __restrict__ W0, short* __restrict__ T0,
    const float* __restrict__ W1, short* __restrict__ T1,
    const float* __restrict__ W2, short* __restrict__ T2,
    const float* __restrict__ W3, short* __restrict__ T3)
{
    __shared__ float t[32][33];
    int bid = blockIdx.x;
    const float* W; short* WT; int K, N, nx, lb;
    if (bid < 1728)      { W = W0; WT = T0; K = 768;  N = 2304; nx = 72; lb = bid; }
    else if (bid < 2304) { W = W1; WT = T1; K = 768;  N = 768;  nx = 24; lb = bid - 1728; }
    else if (bid < 4608) { W = W2; WT = T2; K = 768;  N = 3072; nx = 96; lb = bid - 2304; }
    else                 { W = W3; WT = T3; K = 3072; N = 768;  nx = 24; lb = bid - 4608; }
    int n0 = (lb % nx) * 32, k0 = (lb / nx) * 32;
    int tx = threadIdx.x & 31, ty = threadIdx.x >> 5;
#pragma unroll
    for (int i = 0; i < 32; i += 8)
        t[ty + i][tx] = W[(size_t)(k0 + ty + i) * N + n0 + tx];
    __syncthreads();
#pragma unroll
    for (int i = 0; i < 32; i += 8)
        WT[(size_t)(n0 + ty + i) * K + k0 + tx] = f2bf(t[tx][ty + i]);
}

// ---------------- LayerNorm fp32 -> bf16, one wave per row (C=768) -----
__global__ __launch_bounds__(256) void ln_bf16(
    const float* __restrict__ x, const float* __restrict__ gam,
    const float* __restrict__ bet, short* __restrict__ out)
{
    const int w = threadIdx.x >> 6, lane = threadIdx.x & 63;
    const size_t row = (size_t)blockIdx.x * 4 + w;
    const float* xr = x + row * 768;
    float4 v[3];
    float s = 0.f, ss = 0.f;
#pragma unroll
    for (int k = 0; k < 3; ++k) {
        v[k] = *(const float4*)(xr + k * 256 + lane * 4);
        s  += v[k].x + v[k].y + v[k].z + v[k].w;
        ss += v[k].x * v[k].x + v[k].y * v[k].y + v[k].z * v[k].z + v[k].w * v[k].w;
    }
#pragma unroll
    for (int i = 1; i < 64; i <<= 1) { s += __shfl_xor(s, i, 64); ss += __shfl_xor(ss, i, 64); }
    const float inv = 1.f / 768.f;
    float mu = s * inv;
    float var = ss * inv - mu * mu;
    float rstd = rsqrtf(var + 1e-5f);
#pragma unroll
    for (int k = 0; k < 3; ++k) {
        int c = k * 256 + lane * 4;
        float vv[4] = { v[k].x, v[k].y, v[k].z, v[k].w };
        s16x4 o;
#pragma unroll
        for (int j = 0; j < 4; ++j)
            o[j] = f2bf((vv[j] - mu) * rstd * gam[c + j] + bet[c + j]);
        *(s16x4*)(out + row * 768 + c) = o;
    }
}

// -------- 128x128x32 bf16 GEMM, 16 waves / 1024 threads (r15-proven) ----
// 3-buffer LDS, distance-2 prefetch, counted vmcnt(1) barriers; 16 waves
// (4M x 4N, wave-tile 32x32, acc[2][2]); staging = 1 gload16/thread.
// Occupancy thread-limited at 2 blocks/CU = 32 waves/CU.
// MODE 0: QKV scatter; MODE 1: fp32 = acc+bias+resid; MODE 2: bf16 gelu.
template<int MODE>
DEV void gemm_body(
    const short* __restrict__ A, const short* __restrict__ Bt,
    int M, int N, int K,
    const float* __restrict__ bias, const float* __restrict__ resid,
    float* __restrict__ outf, short* __restrict__ outb,
    short* __restrict__ qo, short* __restrict__ ko, short* __restrict__ vo,
    char* lds)
{
    const int tid = threadIdx.x;
    const int w = tid >> 6, lane = tid & 63;
    const int g = lane >> 4, l15 = lane & 15;
    const int brow = blockIdx.x * 128, bcol = blockIdx.y * 128;
    const int wr = w >> 2, wc = w & 3;          // 4M x 4N waves
    f32x4 acc[2][2] = {};

    int aoff[2], boff[2];
#pragma unroll
    for (int m = 0; m < 2; ++m) {
        int ra = wr * 32 + m * 16 + l15;
        aoff[m] = ra * 64 + ((g * 16) ^ (((ra >> 1) & 3) << 4));
    }
#pragma unroll
    for (int n = 0; n < 2; ++n) {
        int rb = wc * 32 + n * 16 + l15;
        boff[n] = 8192 + rb * 64 + ((g * 16) ^ (((rb >> 1) & 3) << 4));
    }
    const int dStage = tid * 16;
    const char* pSrc;
    {
        int r = dStage >> 6, b = dStage & 63;
        int bs = b ^ (((r >> 1) & 3) << 4);
        pSrc = (tid < 512)
             ? (const char*)(A  + (size_t)(brow + r) * K) + bs
             : (const char*)(Bt + (size_t)(bcol + (r - 128)) * K) + bs;
    }

#define GSTAGE(BUF, OFF) gload16(pSrc + (OFF), lds + (BUF) * 16384 + dStage)

    const int KT = K >> 5;            // 24 or 96: divisible by 3
    GSTAGE(0, 0);
    GSTAGE(1, 64);
    wait1_barrier();

    const int NM = KT / 3;
    for (int mi = 0; mi < NM; ++mi) {
#pragma unroll
        for (int u = 0; u < 3; ++u) {
            const int s = mi * 3 + u;
            if (s + 2 < KT) GSTAGE((u + 2) % 3, (u + 2) * 64);
            bf16x8 af[2], bfg[2];
#pragma unroll
            for (int m = 0; m < 2; ++m)
                af[m]  = *(const bf16x8*)(lds + u * 16384 + aoff[m]);
#pragma unroll
            for (int n = 0; n < 2; ++n)
                bfg[n] = *(const bf16x8*)(lds + u * 16384 + boff[n]);
#pragma unroll
            for (int m = 0; m < 2; ++m)
#pragma unroll
                for (int n = 0; n < 2; ++n)
                    acc[m][n] = __builtin_amdgcn_mfma_f32_16x16x32_bf16(af[m], bfg[n], acc[m][n], 0, 0, 0);
            if (s + 1 < KT) {
                if (s + 2 < KT) wait1_barrier();
                else            wait0_barrier();
            }
        }
        pSrc += 192;
    }
#undef GSTAGE

#pragma unroll
    for (int m = 0; m < 2; ++m) {
#pragma unroll
        for (int n = 0; n < 2; ++n) {
#pragma unroll
            for (int j = 0; j < 4; ++j) {
                int r = brow + wr * 32 + m * 16 + g * 4 + j;
                int c = bcol + wc * 32 + n * 16 + l15;
                float v = acc[m][n][j];
                if (MODE == 0) {
                    int which = c / 768, cc = c % 768;
                    int h = cc >> 6, d = cc & 63;
                    int b_ = r >> 11, nn = r & 2047;
                    size_t bh = (size_t)b_ * 12 + h;
                    // Q pre-scaled by 0.125*log2(e) so attention uses exp2
                    if (which == 0)      qo[(bh * 2048 + nn) * 64 + d] = f2bf(v * 0.18033688011112042f);
                    else if (which == 1) ko[(bh * 2048 + nn) * 64 + d] = f2bf(v);
                    else                 vo[(bh * 64 + d) * 2048 + nn] = f2bf(v);
                } else if (MODE == 1) {
                    outf[(size_t)r * N + c] = v + bias[c] + resid[(size_t)r * N + c];
                } else {
                    float t = v + bias[c];
                    float ge = 0.5f * t * (1.0f + erff(t * 0.70710678118654752f));
                    outb[(size_t)r * N + c] = f2bf(ge);
                }
            }
        }
    }
}

__global__ __launch_bounds__(1024, 8) void g_qkv(
    const short* A, const short* Bt, int M, int N, int K,
    short* qo, short* ko, short* vo)
{
    __shared__ __align__(16) char lds[49152];
    gemm_body<0>(A, Bt, M, N, K, nullptr, nullptr, nullptr, nullptr, qo, ko, vo, lds);
}
__global__ __launch_bounds__(1024, 8) void g_proj(
    const short* A, const short* Bt, int M, int N, int K,
    const float* bias, const float* resid, float* outf)
{
    __shared__ __align__(16) char lds[49152];
    gemm_body<1>(A, Bt, M, N, K, bias, resid, outf, nullptr, nullptr, nullptr, nullptr, lds);
}
__global__ __launch_bounds__(1024, 8) void g_fc1(
    const short* A, const short* Bt, int M, int N, int K,
    const float* bias, short* outb)
{
    __shared__ __align__(16) char lds[49152];
    gemm_body<2>(A, Bt, M, N, K, bias, nullptr, nullptr, outb, nullptr, nullptr, nullptr, lds);
}
__global__ __launch_bounds__(1024, 8) void g_fc2(
    const short* A, const short* Bt, int M, int N, int K,
    const float* bias, const float* resid, float* outf)
{
    __shared__ __align__(16) char lds[49152];
    gemm_body<1>(A, Bt, M, N, K, bias, resid, outf, nullptr, nullptr, nullptr, nullptr, lds);
}

// ---------------- flash attention (r15-proven) --------------------------
// 4 waves x 32 q-rows, KVBLK=32, quad-buffered K/V, distance-3 prefetch,
// counted vmcnt(4), stride-80 P (conflict-free), XCD-aware block swizzle.
__global__ __launch_bounds__(256, 3) void attn_fwd(
    const short* __restrict__ Q, const short* __restrict__ Kg,
    const short* __restrict__ Vt, short* __restrict__ Y)
{
    __shared__ __align__(16) char alds[43008];
    const int tid = threadIdx.x, w = tid >> 6, lane = tid & 63;
    const int g = lane >> 4, l15 = lane & 15;
    const int bid = blockIdx.y * gridDim.x + blockIdx.x;
    const int nwg = gridDim.x * gridDim.y;       // 768, % 8 == 0
    const int logical = (bid & 7) * (nwg >> 3) + (bid >> 3);
    const int bh = logical >> 4;
    const int q0 = (logical & 15) * 128 + w * 32;
    const short* Qb = Q  + (size_t)bh * 2048 * 64;
    const short* Kb = Kg + (size_t)bh * 2048 * 64;
    const short* Vb = Vt + (size_t)bh * 64 * 2048;

    bf16x8 qf[2][2];
#pragma unroll
    for (int m = 0; m < 2; ++m)
#pragma unroll
        for (int kk = 0; kk < 2; ++kk)
            qf[m][kk] = *(const bf16x8*)(Qb + (size_t)(q0 + m * 16 + l15) * 64 + kk * 32 + g * 8);

    f32x4 accO[2][4] = {};
    float lpart[2] = { 0.f, 0.f };

    int koff[2][2], voff[4], poff[2], pwoff[2][2];
#pragma unroll
    for (int n = 0; n < 2; ++n) {
        int key = n * 16 + l15;
#pragma unroll
        for (int kk = 0; kk < 2; ++kk)
            koff[kk][n] = key * 128 + ((kk * 64 + g * 16) ^ ((key & 7) << 4));
    }
#pragma unroll
    for (int n = 0; n < 4; ++n) {
        int d = n * 16 + l15;
        voff[n] = 16384 + d * 64 + ((g * 16) ^ (((d >> 1) & 3) << 4));
    }
#pragma unroll
    for (int m = 0; m < 2; ++m) {
        int qr = m * 16 + l15;
        poff[m] = 32768 + w * 2560 + qr * 80 + g * 16;   // stride-80 P rows
#pragma unroll
        for (int n = 0; n < 2; ++n)
            pwoff[m][n] = 32768 + w * 2560 + qr * 80 + n * 32 + g * 8;
    }
    int dK, dV; const char* pK3; const char* pV3;
    {
        int bb = w * 1024;
        int L = bb + lane * 16;
        int rk = L >> 7, bk_ = L & 127;
        int bsk = bk_ ^ ((rk & 7) << 4);
        dK = bb;
        pK3 = (const char*)(Kb + (size_t)rk * 64) + bsk;
        int rv = L >> 6, bv = L & 63;
        int bsv = bv ^ (((rv >> 1) & 3) << 4);
        dV = bb;
        pV3 = (const char*)(Vb + (size_t)rv * 2048) + bsv;
    }
    gload16(pK3,        alds + dK);
    gload16(pV3,        alds + 16384 + dV);
    gload16(pK3 + 4096, alds + dK + 4096);
    gload16(pV3 + 64,   alds + 16384 + dV + 4096);
    gload16(pK3 + 8192, alds + dK + 8192);
    gload16(pV3 + 128,  alds + 16384 + dV + 8192);
    pK3 += 3 * 4096; pV3 += 3 * 64;
    wait4_barrier();

    for (int tm = 0; tm < 16; ++tm) {
#pragma unroll
        for (int tu = 0; tu < 4; ++tu) {
            const int t = tm * 4 + tu;
            if (t + 3 < 64) {
                gload16(pK3, alds + dK + ((tu + 3) & 3) * 4096);
                gload16(pV3, alds + 16384 + dV + ((tu + 3) & 3) * 4096);
                pK3 += 4096; pV3 += 64;
            }

            f32x4 s2[2][2] = {};
            __builtin_amdgcn_s_setprio(1);
#pragma unroll
            for (int kk = 0; kk < 2; ++kk) {
                bf16x8 kf[2];
#pragma unroll
                for (int n = 0; n < 2; ++n)
                    kf[n] = *(const bf16x8*)(alds + tu * 4096 + koff[kk][n]);
#pragma unroll
                for (int m = 0; m < 2; ++m)
#pragma unroll
                    for (int n = 0; n < 2; ++n)
                        s2[m][n] = __builtin_amdgcn_mfma_f32_16x16x32_bf16(kf[n], qf[m][kk], s2[m][n], 0, 0, 0);
            }
            __builtin_amdgcn_s_setprio(0);

#pragma unroll
            for (int m = 0; m < 2; ++m)
#pragma unroll
                for (int n = 0; n < 2; ++n) {
                    float e0 = __builtin_amdgcn_exp2f(s2[m][n][0]);
                    float e1 = __builtin_amdgcn_exp2f(s2[m][n][1]);
                    float e2 = __builtin_amdgcn_exp2f(s2[m][n][2]);
                    float e3 = __builtin_amdgcn_exp2f(s2[m][n][3]);
                    lpart[m] += (e0 + e1) + (e2 + e3);
                    uint2 pk; pk.x = cvtpk(e0, e1); pk.y = cvtpk(e2, e3);
                    *(uint2*)(alds + pwoff[m][n]) = pk;
                }

            __builtin_amdgcn_s_setprio(1);
            {
                bf16x8 vf[4], pf[2];
#pragma unroll
                for (int n = 0; n < 4; ++n)
                    vf[n] = *(const bf16x8*)(alds + tu * 4096 + voff[n]);
#pragma unroll
                for (int m = 0; m < 2; ++m)
                    pf[m] = *(const bf16x8*)(alds + poff[m]);
#pragma unroll
                for (int m = 0; m < 2; ++m)
#pragma unroll
                    for (int n = 0; n < 4; ++n)
                        accO[m][n] = __builtin_amdgcn_mfma_f32_16x16x32_bf16(pf[m], vf[n], accO[m][n], 0, 0, 0);
            }
            __builtin_amdgcn_s_setprio(0);

            if (t < 61)       wait4_barrier();
            else if (t == 61) wait2_barrier();
            else if (t == 62) wait0_barrier();
        }
    }

#pragma unroll
    for (int m = 0; m < 2; ++m) {
        lpart[m] += __shfl_xor(lpart[m], 16, 64);
        lpart[m] += __shfl_xor(lpart[m], 32, 64);
    }

    int b_ = bh / 12, h = bh % 12;
#pragma unroll
    for (int m = 0; m < 2; ++m) {
        float linv[4];
#pragma unroll
        for (int j = 0; j < 4; ++j)
            linv[j] = 1.0f / __shfl(lpart[m], g * 4 + j, 64);
#pragma unroll
        for (int n = 0; n < 4; ++n)
#pragma unroll
            for (int j = 0; j < 4; ++j) {
                int qq = q0 + m * 16 + g * 4 + j;
                int d = n * 16 + l15;
                Y[((size_t)b_ * 2048 + qq) * 768 + h * 64 + d] = f2bf(accO[m][n][j] * linv[j]);
            }
    }
}

// ---------------- launcher ---------------------------------------------
extern "C" void kernel_launch(void* const* d_in, const int* in_sizes, int n_in,
                              void* d_out, int out_size, void* d_ws, size_t ws_size,
                              hipStream_t stream)
{
    const float* x      = (const float*)d_in[0];
    const float* ln1_g  = (const float*)d_in[1];
    const float* ln1_b  = (const float*)d_in[2];
    const float* w_qkv  = (const float*)d_in[3];
    const float* w_proj = (const float*)d_in[4];
    const float* b_proj = (const float*)d_in[5];
    const float* ln2_g  = (const float*)d_in[6];
    const float* ln2_b  = (const float*)d_in[7];
    const float* w_fc1  = (const float*)d_in[8];
    const float* b_fc1  = (const float*)d_in[9];
    const float* w_fc2  = (const float*)d_in[10];
    const float* b_fc2  = (const float*)d_in[11];

    char* ws = (char*)d_ws;
    size_t off = 0;
    auto alloc = [&](size_t bytes) -> void* {
        void* p = ws + off; off += (bytes + 255) & ~(size_t)255; return p;
    };
    short* wqkvT = (short*)alloc((size_t)2304 * 768 * 2);
    short* wprojT= (short*)alloc((size_t)768 * 768 * 2);
    short* wfc1T = (short*)alloc((size_t)3072 * 768 * 2);
    short* wfc2T = (short*)alloc((size_t)768 * 3072 * 2);
    short* h1    = (short*)alloc((size_t)8192 * 768 * 2);
    short* qb    = (short*)alloc((size_t)48 * 2048 * 64 * 2);
    short* kb    = (short*)alloc((size_t)48 * 2048 * 64 * 2);
    short* vtb   = (short*)alloc((size_t)48 * 64 * 2048 * 2);
    short* yb    = (short*)alloc((size_t)8192 * 768 * 2);
    float* X1    = (float*)alloc((size_t)8192 * 768 * 4);
    short* h2    = (short*)alloc((size_t)8192 * 768 * 2);
    short* h3    = (short*)alloc((size_t)8192 * 3072 * 2);

    tcvt4<<<6912, 256, 0, stream>>>(w_qkv, wqkvT, w_proj, wprojT,
                                    w_fc1, wfc1T, w_fc2, wfc2T);

    ln_bf16<<<2048, 256, 0, stream>>>(x, ln1_g, ln1_b, h1);

    g_qkv<<<dim3(64, 18), 1024, 0, stream>>>(h1, wqkvT, 8192, 2304, 768, qb, kb, vtb);

    attn_fwd<<<dim3(16, 48), 256, 0, stream>>>(qb, kb, vtb, yb);

    g_proj<<<dim3(64, 6), 1024, 0, stream>>>(yb, wprojT, 8192, 768, 768, b_proj, x, X1);

    ln_bf16<<<2048, 256, 0, stream>>>(X1, ln2_g, ln2_b, h2);

    g_fc1<<<dim3(64, 24), 1024, 0, stream>>>(h2, wfc1T, 8192, 3072, 768, b_fc1, h3);

    g_fc2<<<dim3(64, 6), 1024, 0, stream>>>(h3, wfc2T, 8192, 768, 3072, b_fc2, X1, (float*)d_out);
}